// Round 10
// baseline (469.504 us; speedup 1.0000x reference)
//
#include <hip/hip_runtime.h>

#define N_NODES 10000
#define N_EDGES 40000
#define HD 64
#define MAXD 12
#define CAP 32
#define Y2ROW ((size_t)(N_NODES + 1) * 128)  // per-edge-type y stride in uints (bf16-packed)
#define LOG2E 1.44269504f
#define XST 148  // edge-head LDS row stride (floats)

typedef __attribute__((ext_vector_type(8))) short short8;
typedef __attribute__((ext_vector_type(4))) float floatx4;

#define MFMA16(A, B, C) __builtin_amdgcn_mfma_f32_16x16x32_bf16(A, B, C, 0, 0, 0)

#if __has_builtin(__builtin_amdgcn_exp2f)
#define EXP2(x) __builtin_amdgcn_exp2f(x)
#else
#define EXP2(x) __expf((x) * 0.6931471806f)
#endif

__device__ __forceinline__ float sigmoidf_(float x) {
  return 1.0f / (1.0f + __expf(-x));
}
__device__ __forceinline__ float fma4(float4 w, float4 x, float a) {
  a = fmaf(w.x, x.x, a);
  a = fmaf(w.y, x.y, a);
  a = fmaf(w.z, x.z, a);
  return fmaf(w.w, x.w, a);
}

// split 8 consecutive fp32 into bf16 hi/lo fragments
__device__ __forceinline__ void split_frag(float4 a, float4 b, short8& hi, short8& lo) {
  float f[8] = {a.x, a.y, a.z, a.w, b.x, b.y, b.z, b.w};
  union { short8 v; unsigned d[4]; } H, L;
#pragma unroll
  for (int p = 0; p < 4; ++p) {
    unsigned u0 = __float_as_uint(f[2 * p]);
    unsigned u1 = __float_as_uint(f[2 * p + 1]);
    H.d[p] = (u0 >> 16) | (u1 & 0xFFFF0000u);
    float l0 = f[2 * p] - __uint_as_float(u0 & 0xFFFF0000u);
    float l1 = f[2 * p + 1] - __uint_as_float(u1 & 0xFFFF0000u);
    L.d[p] = (__float_as_uint(l0) >> 16) | (__float_as_uint(l1) & 0xFFFF0000u);
  }
  hi = H.v;
  lo = L.v;
}

// ---------------- adjacency build ----------------

__global__ void scatter_kernel(const int* __restrict__ edges, int* __restrict__ cnt,
                               int* __restrict__ pool) {
  int idx = blockIdx.x * 256 + threadIdx.x;
  if (idx >= 4 * N_EDGES) return;
  int et = idx / N_EDGES, e = idx - et * N_EDGES;
  int src = edges[(et * 2) * N_EDGES + e];
  int dst = edges[(et * 2 + 1) * N_EDGES + e];
  int slot = atomicAdd(&cnt[et * N_NODES + dst], 1);
  if (slot < CAP) pool[(et * N_NODES + dst) * CAP + slot] = src;
}

__global__ void sortrows_kernel(const int* __restrict__ cnt, const int* __restrict__ pool,
                                int* __restrict__ nbr) {
  __shared__ int buf[64][CAP + 1];
  int idx = blockIdx.x * 64 + threadIdx.x;
  if (idx >= 4 * N_NODES) return;
  int n = idx % N_NODES;
  int c = cnt[idx];
  if (c > CAP) c = CAP;
  int* a = buf[threadIdx.x];
  const int* row = pool + idx * CAP;
  for (int j = 0; j < c; ++j) a[j] = row[j] * 2;
  a[c] = n * 2 + 1;  // self loop sorts after equal-src originals (stable argsort semantics)
  ++c;
  for (int i2 = 1; i2 < c; ++i2) {
    int key = a[i2];
    int b = i2 - 1;
    while (b >= 0 && a[b] > key) { a[b + 1] = a[b]; --b; }
    a[b + 1] = key;
  }
  int* onbr = nbr + idx * MAXD;
  for (int t = 0; t < MAXD; ++t) onbr[t] = (t < c) ? (a[t] >> 1) : N_NODES;
}

// ---------------- fused weight prep ----------------

__device__ __forceinline__ void wfrag_body(const float* __restrict__ W,
                                           short* __restrict__ w16, int gid) {
  int lane = gid & 63;
  int combo = gid >> 6;
  int kc = combo & 1;
  int g = (combo >> 1) & 3;
  int w = (combo >> 3) & 3;
  int i = combo >> 5;
  float sc = (g == 2) ? (2.0f * LOG2E) : LOG2E;
  int gate = g * 64 + w * 16 + (lane & 15);
  int k0 = kc * 32 + (lane >> 4) * 8;
  const float* src = W + ((size_t)i * 256 + gate) * 64 + k0;
  float4 a = ((const float4*)src)[0];
  float4 b = ((const float4*)src)[1];
  a.x *= sc; a.y *= sc; a.z *= sc; a.w *= sc;
  b.x *= sc; b.y *= sc; b.z *= sc; b.w *= sc;
  short8 hi, lo;
  split_frag(a, b, hi, lo);
  short8* dst = (short8*)w16;
  dst[(combo * 2 + 0) * 64 + lane] = hi;
  dst[(combo * 2 + 1) * 64 + lane] = lo;
}

__device__ __forceinline__ void wfrag_body_noscale(const float* __restrict__ W,
                                                   short* __restrict__ w16, int gid) {
  int lane = gid & 63;
  int combo = gid >> 6;
  int kc = combo & 1;
  int g = (combo >> 1) & 3;
  int w = (combo >> 3) & 3;
  int i = combo >> 5;
  int gate = g * 64 + w * 16 + (lane & 15);
  int k0 = kc * 32 + (lane >> 4) * 8;
  const float* src = W + ((size_t)i * 256 + gate) * 64 + k0;
  float4 a = ((const float4*)src)[0];
  float4 b = ((const float4*)src)[1];
  short8 hi, lo;
  split_frag(a, b, hi, lo);
  short8* dst = (short8*)w16;
  dst[(combo * 2 + 0) * 64 + lane] = hi;
  dst[(combo * 2 + 1) * 64 + lane] = lo;
}

__device__ __forceinline__ void cw_body(const float* __restrict__ Wl,
    const float* __restrict__ Wr, short* __restrict__ cw, int gid) {
  int lane = gid & 63;
  int rest = gid >> 6;
  int combo = rest & 7;
  int mat = (rest >> 3) % 3;
  int pair = rest / 24;
  int L = pair >> 1, side = pair & 1;
  int iA = L * 4 + (side ? 1 : 0);
  int iB = L * 4 + (side ? 2 : 3);
  int wp = combo >> 1, kc = combo & 1;
  int row = wp * 16 + (lane & 15);
  int k0 = kc * 32 + (lane >> 4) * 8;
  float4 a, b;
  if (mat == 0) {
    const float* s = Wl + ((size_t)iA * 64 + row) * 64 + k0;
    a = ((const float4*)s)[0]; b = ((const float4*)s)[1];
  } else if (mat == 1) {
    const float* s = Wl + ((size_t)iB * 64 + row) * 64 + k0;
    a = ((const float4*)s)[0]; b = ((const float4*)s)[1];
  } else {
    const float* sA = Wr + ((size_t)iA * 64 + row) * 64 + k0;
    const float* sB = Wr + ((size_t)iB * 64 + row) * 64 + k0;
    float4 a1 = ((const float4*)sA)[0], b1 = ((const float4*)sA)[1];
    float4 a2 = ((const float4*)sB)[0], b2 = ((const float4*)sB)[1];
    a.x = a1.x + a2.x; a.y = a1.y + a2.y; a.z = a1.z + a2.z; a.w = a1.w + a2.w;
    b.x = b1.x + b2.x; b.y = b1.y + b2.y; b.z = b1.z + b2.z; b.w = b1.w + b2.w;
  }
  short8 hi, lo;
  split_frag(a, b, hi, lo);
  short8* dst = (short8*)cw;
  int base = ((pair * 3 + mat) * 8 + combo) * 2;
  dst[(base + 0) * 64 + lane] = hi;
  dst[(base + 1) * 64 + lane] = lo;
}

__device__ __forceinline__ void eh_body(const float* __restrict__ Wg1,
    const float* __restrict__ Wm1, const float* __restrict__ Wm2,
    short* __restrict__ ehw16, int gid) {
  int lane = gid & 63;
  int combo = gid >> 6;
  int n = lane & 15, quad = lane >> 4;
  int mat, wp, kc;
  if (combo < 16) { mat = 0; wp = combo >> 2; kc = combo & 3; }
  else if (combo < 28) { int c2 = combo - 16; mat = 1; wp = c2 / 3; kc = c2 % 3; }
  else { int c2 = combo - 28; mat = 2; wp = c2 >> 1; kc = c2 & 1; }
  int row = wp * 16 + n;
  int k0 = kc * 32 + quad * 8;
  float4 a = {0.f, 0.f, 0.f, 0.f}, b = {0.f, 0.f, 0.f, 0.f};
  if (mat == 0) {
    const float* s = Wg1 + (size_t)row * 128 + k0;
    a = ((const float4*)s)[0]; b = ((const float4*)s)[1];
  } else if (mat == 1) {
    if (k0 + 8 <= 80) {
      const float* s = Wm1 + (size_t)row * 80 + k0;
      a = ((const float4*)s)[0]; b = ((const float4*)s)[1];
    }
  } else {
    const float* s = Wm2 + (size_t)row * 64 + k0;
    a = ((const float4*)s)[0]; b = ((const float4*)s)[1];
  }
  short8 hi, lo;
  split_frag(a, b, hi, lo);
  short8* dst = (short8*)ehw16;
  dst[(combo * 2 + 0) * 64 + lane] = hi;
  dst[(combo * 2 + 1) * 64 + lane] = lo;
}

__global__ __launch_bounds__(256) void prep_all_kernel(
    const float* __restrict__ Whh, const float* __restrict__ Wih,
    const float* __restrict__ Wl, const float* __restrict__ Wr,
    const float* __restrict__ Wg1, const float* __restrict__ Wm1,
    const float* __restrict__ Wm2,
    short* __restrict__ whh16, short* __restrict__ wih16, short* __restrict__ cw16,
    short* __restrict__ ehw16, unsigned* __restrict__ ybase, int* __restrict__ cnt) {
  int gid = blockIdx.x * 256 + threadIdx.x;
  if (gid < 24576) {
    wfrag_body(Whh, whh16, gid);
  } else if (gid < 49152) {
    wfrag_body_noscale(Wih, wih16, gid - 24576);
  } else if (gid < 58368) {
    cw_body(Wl, Wr, cw16, gid - 49152);
  } else if (gid < 60416) {
    eh_body(Wg1, Wm1, Wm2, ehw16, gid - 58368);
  } else if (gid < 60928) {
    int t = gid - 60416;  // 4 ets x 128 uints: dummy zero row
    int et = t >> 7, col = t & 127;
    ybase[(size_t)et * Y2ROW + (size_t)N_NODES * 128 + col] = 0u;
  } else if (gid < 60928 + 4 * N_NODES) {
    cnt[gid - 60928] = 0;  // fused cnt memset
  }
}

// ---------------- node encoders ----------------

template <int IN>
__device__ __forceinline__ void encode_body(const float* __restrict__ x,
    const float* __restrict__ W1, const float* __restrict__ b1,
    const float* __restrict__ W2, const float* __restrict__ b2, float* __restrict__ out) {
  __shared__ float xs[4][IN];
  __shared__ float h1[4][HD];
  int w = threadIdx.x >> 6, l = threadIdx.x & 63;
  int n = blockIdx.x * 4 + w;
  if (l < IN) xs[w][l] = x[n * IN + l];
  __syncthreads();
  float acc = b1[l];
#pragma unroll
  for (int k = 0; k < IN; ++k) acc = fmaf(xs[w][k], W1[l * IN + k], acc);
  h1[w][l] = fmaxf(acc, 0.0f);
  __syncthreads();
  float acc2 = b2[l];
#pragma unroll
  for (int k = 0; k < HD; ++k) acc2 = fmaf(h1[w][k], W2[l * HD + k], acc2);
  out[n * HD + l] = acc2;
}

__global__ __launch_bounds__(256) void encode_both_kernel(
    const float* __restrict__ xs0, const float* __restrict__ xt0,
    const float* __restrict__ Ws1, const float* __restrict__ bs1,
    const float* __restrict__ Ws2, const float* __restrict__ bs2,
    const float* __restrict__ Wt1, const float* __restrict__ bt1,
    const float* __restrict__ Wt2, const float* __restrict__ bt2,
    float* __restrict__ outS, float* __restrict__ outT) {
  if (blockIdx.y == 0) encode_body<32>(xs0, Ws1, bs1, Ws2, bs2, outS);
  else encode_body<24>(xt0, Wt1, bt1, Wt2, bt2, outT);
}

// ---------------- y = x @ Wih.T via MFMA; output packed bf16 [node][u] = uint2 ----------------

__global__ __launch_bounds__(256) void ygemm_mfma_kernel(const float* __restrict__ xs0,
    const float* __restrict__ xt0, const short* __restrict__ wih16L, unsigned* __restrict__ ybase) {
  __shared__ __align__(16) float xS[16][68];
  __shared__ __align__(16) float pS[16][260];
  int et = blockIdx.y;
  const float* x = (et == 0 || et == 2) ? xs0 : xt0;
  const short8* wf = (const short8*)(wih16L + (size_t)et * 32768);
  unsigned* y = ybase + (size_t)et * Y2ROW;
  int tid = threadIdx.x, w = tid >> 6, l = tid & 63;
  int quad = l >> 4, n = l & 15;
  int n0 = blockIdx.x * 16;
  {
    int node = tid >> 4, f4 = tid & 15;
    float4 v = *(const float4*)(x + (size_t)(n0 + node) * 64 + f4 * 4);
    *(float4*)&xS[node][f4 * 4] = v;
  }
  short8 Bh[4][2], Bl[4][2];
#pragma unroll
  for (int wp = 0; wp < 4; ++wp)
#pragma unroll
    for (int kc = 0; kc < 2; ++kc) {
      int combo = (wp * 4 + w) * 2 + kc;
      Bh[wp][kc] = wf[(combo * 2 + 0) * 64 + l];
      Bl[wp][kc] = wf[(combo * 2 + 1) * 64 + l];
    }
  __syncthreads();
  short8 Ah[2], Al[2];
  {
    const float* hp = &xS[n][quad * 8];
    float4 q0 = *(const float4*)hp, q1 = *(const float4*)(hp + 4);
    float4 q2 = *(const float4*)(hp + 32), q3 = *(const float4*)(hp + 36);
    split_frag(q0, q1, Ah[0], Al[0]);
    split_frag(q2, q3, Ah[1], Al[1]);
  }
  floatx4 acc[4];
#pragma unroll
  for (int wp = 0; wp < 4; ++wp) {
    floatx4 a = {0.f, 0.f, 0.f, 0.f};
    a = MFMA16(Ah[0], Bh[wp][0], a);
    a = MFMA16(Ah[1], Bh[wp][1], a);
    a = MFMA16(Al[0], Bh[wp][0], a);
    a = MFMA16(Al[1], Bh[wp][1], a);
    a = MFMA16(Ah[0], Bl[wp][0], a);
    a = MFMA16(Ah[1], Bl[wp][1], a);
    acc[wp] = a;
  }
#pragma unroll
  for (int wp = 0; wp < 4; ++wp)
#pragma unroll
    for (int r = 0; r < 4; ++r)
      pS[quad * 4 + r][(wp * 16 + n) * 4 + w] = acc[wp][r];
  __syncthreads();
#pragma unroll
  for (int cc = 0; cc < 4; ++cc) {
    int g4 = cc * 256 + tid;
    int node = g4 >> 6, u = g4 & 63;
    const float* p = &pS[node][u * 4];
    unsigned r0 = __float_as_uint(p[0]) + 0x8000u;
    unsigned r1 = __float_as_uint(p[1]) + 0x8000u;
    unsigned r2 = __float_as_uint(p[2]) + 0x8000u;
    unsigned r3 = __float_as_uint(p[3]) + 0x8000u;
    uint2 v;
    v.x = __builtin_amdgcn_perm(r1, r0, 0x07060302u);
    v.y = __builtin_amdgcn_perm(r3, r2, 0x07060302u);
    ((uint2*)(y + (size_t)(n0 + node) * 128))[u] = v;
  }
}

// ---------------- SAGE-LSTM aggregation ----------------
// Step restructured so the y-gather loads are issued immediately AFTER the
// per-step barrier and consumed in gate-math one full step later — the
// compiler's vmcnt(0) drain at the next s_barrier then sees ~step-old loads
// (no stall). y enters via gate-add instead of MFMA C-init (fp reassoc only).

__global__ __launch_bounds__(256) void lstm_mfma_kernel(const int* __restrict__ nbrAll,
    const unsigned* __restrict__ ybase, const short* __restrict__ whh16L,
    const float* __restrict__ bihL, const float* __restrict__ bhhL, float* __restrict__ aggBase) {
  __shared__ __align__(16) unsigned pkS[2][16 * 68];
  __shared__ int nbS[16][MAXD];
  int et = blockIdx.y;
  const int* nbr = nbrAll + (size_t)et * N_NODES * MAXD;
  const uint2* y2 = (const uint2*)(ybase + (size_t)et * Y2ROW);
  const short* whh16 = whh16L + (size_t)et * 32768;
  const float* bih = bihL + et * 256;
  const float* bhh = bhhL + et * 256;
  float* agg = aggBase + (size_t)et * N_NODES * HD;
  int tid = threadIdx.x, w = tid >> 6, l = tid & 63;
  int quad = l >> 4, n = l & 15, u = w * 16 + n;
  int n0 = blockIdx.x * 16;
  if (tid < 16 * MAXD) ((int*)nbS)[tid] = nbr[n0 * MAXD + tid];
  short8 Bh[4][2], Bl[4][2];
  {
    const short8* wf = (const short8*)whh16;
#pragma unroll
    for (int g = 0; g < 4; ++g)
#pragma unroll
      for (int kc = 0; kc < 2; ++kc) {
        int combo = (w * 4 + g) * 2 + kc;
        Bh[g][kc] = wf[(combo * 2 + 0) * 64 + l];
        Bl[g][kc] = wf[(combo * 2 + 1) * 64 + l];
      }
  }
  float bs[4];
#pragma unroll
  for (int g = 0; g < 4; ++g)
    bs[g] = (bih[g * 64 + u] + bhh[g * 64 + u]) * ((g == 2) ? (2.0f * LOG2E) : LOG2E);
  float c[4] = {0.f, 0.f, 0.f, 0.f}, h[4];
  short8 Ah[2], Al[2];
#pragma unroll
  for (int kc = 0; kc < 2; ++kc) { Ah[kc] = (short8)0; Al[kc] = (short8)0; }
  __syncthreads();
  uint2 Y[4];
#pragma unroll
  for (int r = 0; r < 4; ++r) Y[r] = y2[(size_t)nbS[quad * 4 + r][0] * 64 + u];
  for (int t = 0; t < MAXD; ++t) {
    // MFMA first (no dependence on Y): two independent 3-chains per gate
    floatx4 acc[4];
#pragma unroll
    for (int g = 0; g < 4; ++g) {
      floatx4 a1 = {0.f, 0.f, 0.f, 0.f};
      floatx4 a2 = {0.f, 0.f, 0.f, 0.f};
      a1 = MFMA16(Ah[0], Bh[g][0], a1);
      a1 = MFMA16(Ah[1], Bh[g][1], a1);
      a1 = MFMA16(Al[0], Bh[g][0], a1);
      a2 = MFMA16(Al[1], Bh[g][1], a2);
      a2 = MFMA16(Ah[0], Bl[g][0], a2);
      a2 = MFMA16(Ah[1], Bl[g][1], a2);
      acc[g] = a1 + a2;
    }
    // consume Y here (vmcnt wait; loads are one full step old)
    float yg[4][4];
#pragma unroll
    for (int r = 0; r < 4; ++r) {
      yg[0][r] = __uint_as_float(Y[r].x << 16);
      yg[1][r] = __uint_as_float(Y[r].x & 0xFFFF0000u);
      yg[2][r] = __uint_as_float(Y[r].y << 16);
      yg[3][r] = __uint_as_float(Y[r].y & 0xFFFF0000u);
    }
    int buf = (t + 1) & 1;
#pragma unroll
    for (int r = 0; r < 4; ++r) {
      float gi = acc[0][r] + (yg[0][r] + bs[0]);
      float gf = acc[1][r] + (yg[1][r] + bs[1]);
      float gg = acc[2][r] + (yg[2][r] + bs[2]);
      float go = acc[3][r] + (yg[3][r] + bs[3]);
      float a_ = EXP2(-gi);
      float b_ = EXP2(fminf(-gg, 60.f));
      float f_ = EXP2(-gf);
      float o_ = EXP2(-go);
      float p1 = 1.f + a_, p2 = 1.f + b_, p3 = 1.f + f_;
      float d1 = p1 * p2;
      float num = fmaf(c[r], d1, (1.f - b_) * p3);
      c[r] = num * __builtin_amdgcn_rcpf(p3 * d1);
      float e_ = EXP2(c[r] * (-2.0f * LOG2E));
      h[r] = (1.f - e_) * __builtin_amdgcn_rcpf((1.f + e_) * (1.f + o_));
      unsigned ub = __float_as_uint(h[r]);
      float lo = h[r] - __uint_as_float(ub & 0xFFFF0000u);
      pkS[buf][(quad * 4 + r) * 68 + u] =
          __builtin_amdgcn_perm(ub, __float_as_uint(lo), 0x07060302u);
    }
    if (t + 1 < MAXD) {
      __syncthreads();
      // issue next step's gathers right AFTER the barrier: a full step of
      // slack before consumption and before the next barrier's vmcnt drain
#pragma unroll
      for (int r = 0; r < 4; ++r) Y[r] = y2[(size_t)nbS[quad * 4 + r][t + 1] * 64 + u];
#pragma unroll
      for (int kc = 0; kc < 2; ++kc) {
        const unsigned* pb = &pkS[buf][n * 68 + kc * 32 + quad * 8];
        uint4 qa = *(const uint4*)pb;
        uint4 qb = *(const uint4*)(pb + 4);
        union { short8 s; unsigned d[4]; } H, L;
        H.d[0] = __builtin_amdgcn_perm(qa.y, qa.x, 0x07060302u);
        H.d[1] = __builtin_amdgcn_perm(qa.w, qa.z, 0x07060302u);
        H.d[2] = __builtin_amdgcn_perm(qb.y, qb.x, 0x07060302u);
        H.d[3] = __builtin_amdgcn_perm(qb.w, qb.z, 0x07060302u);
        L.d[0] = __builtin_amdgcn_perm(qa.y, qa.x, 0x05040100u);
        L.d[1] = __builtin_amdgcn_perm(qa.w, qa.z, 0x05040100u);
        L.d[2] = __builtin_amdgcn_perm(qb.y, qb.x, 0x05040100u);
        L.d[3] = __builtin_amdgcn_perm(qb.w, qb.z, 0x05040100u);
        Ah[kc] = H.s;
        Al[kc] = L.s;
      }
    }
  }
#pragma unroll
  for (int r = 0; r < 4; ++r)
    agg[(size_t)(n0 + quad * 4 + r) * HD + u] = h[r];
}

// ---------------- combine via MFMA ----------------

__global__ __launch_bounds__(256) void combine_mfma_kernel(const float* __restrict__ aggBase,
    const short* __restrict__ cwL, const float* __restrict__ blL,
    const float* __restrict__ xS0, const float* __restrict__ xT0, int has_res,
    float* __restrict__ outS, float* __restrict__ outT) {
  __shared__ __align__(16) float tS[3][16][68];
  int side = blockIdx.y;
  int etA = side ? 1 : 0, etB = side ? 2 : 3;
  const float* srcs[3];
  srcs[0] = aggBase + (size_t)etA * N_NODES * HD;
  srcs[1] = aggBase + (size_t)etB * N_NODES * HD;
  srcs[2] = side ? xT0 : xS0;
  float* out = side ? outT : outS;
  const short8* wf = (const short8*)cwL + (size_t)side * 3072;
  const float* blA = blL + etA * 64;
  const float* blB = blL + etB * 64;
  int tid = threadIdx.x, w = tid >> 6, l = tid & 63;
  int quad = l >> 4, n = l & 15;
  int n0 = blockIdx.x * 16;
  {
    int node = tid >> 4, f4 = tid & 15;
#pragma unroll
    for (int m = 0; m < 3; ++m) {
      float4 v = *(const float4*)(srcs[m] + (size_t)(n0 + node) * 64 + f4 * 4);
      *(float4*)&tS[m][node][f4 * 4] = v;
    }
  }
  short8 Bh[3][2], Bl[3][2];
#pragma unroll
  for (int m = 0; m < 3; ++m)
#pragma unroll
    for (int kc = 0; kc < 2; ++kc) {
      int base = (m * 8 + w * 2 + kc) * 2;
      Bh[m][kc] = wf[(base + 0) * 64 + l];
      Bl[m][kc] = wf[(base + 1) * 64 + l];
    }
  float bsum = blA[w * 16 + n] + blB[w * 16 + n];
  __syncthreads();
  floatx4 a = {0.f, 0.f, 0.f, 0.f};
#pragma unroll
  for (int m = 0; m < 3; ++m) {
    short8 Ah[2], Al[2];
    const float* hp = &tS[m][n][quad * 8];
    float4 q0 = *(const float4*)hp, q1 = *(const float4*)(hp + 4);
    float4 q2 = *(const float4*)(hp + 32), q3 = *(const float4*)(hp + 36);
    split_frag(q0, q1, Ah[0], Al[0]);
    split_frag(q2, q3, Ah[1], Al[1]);
    a = MFMA16(Ah[0], Bh[m][0], a);
    a = MFMA16(Ah[1], Bh[m][1], a);
    a = MFMA16(Al[0], Bh[m][0], a);
    a = MFMA16(Al[1], Bh[m][1], a);
    a = MFMA16(Ah[0], Bl[m][0], a);
    a = MFMA16(Ah[1], Bl[m][1], a);
  }
#pragma unroll
  for (int r = 0; r < 4; ++r) {
    int node = quad * 4 + r;
    float v = 0.5f * (a[r] + bsum);
    if (has_res) v += tS[2][node][w * 16 + n];
    out[(size_t)(n0 + node) * 64 + w * 16 + n] = fmaxf(v, 0.f);
  }
}

// ---------------- edge head via MFMA ----------------

__global__ __launch_bounds__(256) void edge_head_mfma_kernel(
    const int* __restrict__ esrc, const int* __restrict__ edst, const float* __restrict__ ea,
    const float* __restrict__ s3, const float* __restrict__ t3,
    const short* __restrict__ ehw16,
    const float* __restrict__ bg1, const float* __restrict__ Wg2,
    const float* __restrict__ bg2, const float* __restrict__ bm1,
    const float* __restrict__ bm2, const float* __restrict__ Wm3,
    const float* __restrict__ bm3, float* __restrict__ out) {
  __shared__ __align__(16) float xS[64][XST];
  __shared__ float gP[4][64];
  int tid = threadIdx.x, w = tid >> 6, l = tid & 63;
  int quad = l >> 4, n = l & 15;
  int e0 = blockIdx.x * 64;
  const short8* wf = (const short8*)ehw16;
  for (int idx = tid; idx < 2048; idx += 256) {
    int e = idx >> 5, kk = idx & 31;
    float4 v;
    if (kk < 16) v = ((const float4*)(s3 + (size_t)esrc[e0 + e] * 64))[kk];
    else         v = ((const float4*)(t3 + (size_t)edst[e0 + e] * 64))[kk - 16];
    *(float4*)&xS[e][kk * 4] = v;
  }
  {
    int e = tid >> 2, kk = tid & 3;
    *(float4*)&xS[e][128 + kk * 4] = ((const float4*)(ea + (size_t)(e0 + e) * 16))[kk];
  }
  __syncthreads();
  {
    short8 Bh[4], Bl[4];
#pragma unroll
    for (int kc = 0; kc < 4; ++kc) {
      int cb = w * 4 + kc;
      Bh[kc] = wf[(cb * 2 + 0) * 64 + l];
      Bl[kc] = wf[(cb * 2 + 1) * 64 + l];
    }
    float bg = bg1[w * 16 + n];
    float wg2l = Wg2[w * 16 + n];
    float red[4][4];
#pragma unroll
    for (int mt = 0; mt < 4; ++mt) {
      floatx4 a = {bg, bg, bg, bg};
#pragma unroll
      for (int kc = 0; kc < 4; ++kc) {
        const float* hp = &xS[mt * 16 + n][kc * 32 + quad * 8];
        float4 q0 = *(const float4*)hp, q1 = *(const float4*)(hp + 4);
        short8 Ah, Al;
        split_frag(q0, q1, Ah, Al);
        a = MFMA16(Ah, Bh[kc], a);
        a = MFMA16(Al, Bh[kc], a);
        a = MFMA16(Ah, Bl[kc], a);
      }
#pragma unroll
      for (int r = 0; r < 4; ++r) red[mt][r] = fmaxf(a[r], 0.f) * wg2l;
    }
#pragma unroll
    for (int mt = 0; mt < 4; ++mt)
#pragma unroll
      for (int r = 0; r < 4; ++r) {
#pragma unroll
        for (int off = 1; off < 16; off <<= 1)
          red[mt][r] += __shfl_xor(red[mt][r], off);
      }
#pragma unroll
    for (int mt = 0; mt < 4; ++mt)
#pragma unroll
      for (int r = 0; r < 4; ++r)
        if (n == mt * 4 + r) gP[w][mt * 16 + quad * 4 + r] = red[mt][r];
  }
  __syncthreads();
  float gv[4];
  {
    float b2 = bg2[0];
#pragma unroll
    for (int mt = 0; mt < 4; ++mt) {
      int e = mt * 16 + n;
      float p = gP[0][e] + gP[1][e] + gP[2][e] + gP[3][e] + b2;
      gv[mt] = sigmoidf_(p);
    }
  }
  floatx4 acc2[4];
  {
    short8 Bh[3], Bl[3];
#pragma unroll
    for (int kc = 0; kc < 3; ++kc) {
      int cb = 16 + w * 3 + kc;
      Bh[kc] = wf[(cb * 2 + 0) * 64 + l];
      Bl[kc] = wf[(cb * 2 + 1) * 64 + l];
    }
    float bm = bm1[w * 16 + n];
#pragma unroll
    for (int mt = 0; mt < 4; ++mt) {
      int e = mt * 16 + n;
      float g = gv[mt];
      floatx4 a = {bm, bm, bm, bm};
#pragma unroll
      for (int kc = 0; kc < 2; ++kc) {
        const float* sp = &xS[e][kc * 32 + quad * 8];
        float4 s0 = *(const float4*)sp, s1 = *(const float4*)(sp + 4);
        float4 t0 = *(const float4*)(sp + 64), t1 = *(const float4*)(sp + 68);
        float4 e0v, e1v;
        e0v.x = fmaf(g, s0.x - t0.x, t0.x); e0v.y = fmaf(g, s0.y - t0.y, t0.y);
        e0v.z = fmaf(g, s0.z - t0.z, t0.z); e0v.w = fmaf(g, s0.w - t0.w, t0.w);
        e1v.x = fmaf(g, s1.x - t1.x, t1.x); e1v.y = fmaf(g, s1.y - t1.y, t1.y);
        e1v.z = fmaf(g, s1.z - t1.z, t1.z); e1v.w = fmaf(g, s1.w - t1.w, t1.w);
        short8 Ah, Al;
        split_frag(e0v, e1v, Ah, Al);
        a = MFMA16(Ah, Bh[kc], a);
        a = MFMA16(Al, Bh[kc], a);
        a = MFMA16(Ah, Bl[kc], a);
      }
      {
        float4 z0 = {0.f, 0.f, 0.f, 0.f}, z1 = {0.f, 0.f, 0.f, 0.f};
        if (quad < 2) {
          const float* ap = &xS[e][128 + quad * 8];
          z0 = *(const float4*)ap;
          z1 = *(const float4*)(ap + 4);
        }
        short8 Ah, Al;
        split_frag(z0, z1, Ah, Al);
        a = MFMA16(Ah, Bh[2], a);
        a = MFMA16(Al, Bh[2], a);
        a = MFMA16(Ah, Bl[2], a);
      }
      acc2[mt] = a;
    }
  }
  __syncthreads();
#pragma unroll
  for (int mt = 0; mt < 4; ++mt)
#pragma unroll
    for (int r = 0; r < 4; ++r)
      xS[mt * 16 + quad * 4 + r][w * 16 + n] = fmaxf(acc2[mt][r], 0.f);
  __syncthreads();
  {
    int s = w & 1, mtb = (w >> 1) * 2;
    short8 Bh[2], Bl[2];
#pragma unroll
    for (int kc = 0; kc < 2; ++kc) {
      int cb = 28 + s * 2 + kc;
      Bh[kc] = wf[(cb * 2 + 0) * 64 + l];
      Bl[kc] = wf[(cb * 2 + 1) * 64 + l];
    }
    float bm = bm2[s * 16 + n];
#pragma unroll
    for (int mi = 0; mi < 2; ++mi) {
      int mt = mtb + mi;
      int e = mt * 16 + n;
      floatx4 a = {bm, bm, bm, bm};
#pragma unroll
      for (int kc = 0; kc < 2; ++kc) {
        const float* sp = &xS[e][kc * 32 + quad * 8];
        float4 q0 = *(const float4*)sp, q1 = *(const float4*)(sp + 4);
        short8 Ah, Al;
        split_frag(q0, q1, Ah, Al);
        a = MFMA16(Ah, Bh[kc], a);
        a = MFMA16(Al, Bh[kc], a);
        a = MFMA16(Ah, Bl[kc], a);
      }
#pragma unroll
      for (int r = 0; r < 4; ++r)
        xS[mt * 16 + quad * 4 + r][64 + s * 16 + n] = fmaxf(a[r], 0.f);
    }
  }
  __syncthreads();
  if (tid < 128) {
    int e = tid >> 1, j = tid & 1;
    const float4* hp = (const float4*)&xS[e][64];
    const float4* w3 = (const float4*)(Wm3 + j * 32);
    float a = bm3[j];
#pragma unroll
    for (int kk = 0; kk < 8; ++kk) a = fma4(w3[kk], hp[kk], a);
    out[(e0 + e) * 2 + j] = a;
  }
}

// ---------------- host orchestration ----------------

extern "C" void kernel_launch(void* const* d_in, const int* in_sizes, int n_in, void* d_out,
                              int out_size, void* d_ws, size_t ws_size, hipStream_t stream) {
  const float* x_source = (const float*)d_in[0];
  const float* x_target = (const float*)d_in[1];
  const int* edges = (const int*)d_in[2];
  const float* edge_attr = (const float*)d_in[3];
  const float* We_s1 = (const float*)d_in[4];
  const float* be_s1 = (const float*)d_in[5];
  const float* We_s2 = (const float*)d_in[6];
  const float* be_s2 = (const float*)d_in[7];
  const float* We_t1 = (const float*)d_in[8];
  const float* be_t1 = (const float*)d_in[9];
  const float* We_t2 = (const float*)d_in[10];
  const float* be_t2 = (const float*)d_in[11];
  const float* Wih = (const float*)d_in[12];
  const float* Whh = (const float*)d_in[13];
  const float* bih = (const float*)d_in[14];
  const float* bhh = (const float*)d_in[15];
  const float* Wl = (const float*)d_in[16];
  const float* bl = (const float*)d_in[17];
  const float* Wr = (const float*)d_in[18];
  const float* Wg1 = (const float*)d_in[19];
  const float* bg1 = (const float*)d_in[20];
  const float* Wg2 = (const float*)d_in[21];
  const float* bg2 = (const float*)d_in[22];
  const float* Wm1 = (const float*)d_in[23];
  const float* bm1 = (const float*)d_in[24];
  const float* Wm2 = (const float*)d_in[25];
  const float* bm2 = (const float*)d_in[26];
  const float* Wm3 = (const float*)d_in[27];
  const float* bm3 = (const float*)d_in[28];
  float* out = (float*)d_out;

  int* nbr = (int*)d_ws;                       // 4*N*12
  int* cnt = nbr + 4 * N_NODES * MAXD;         // 4*N
  int* pool = cnt + 4 * N_NODES;               // 4*N*CAP
  float* fb = (float*)(pool + 4 * N_NODES * CAP);
  float* bufS[2] = {fb, fb + N_NODES * HD};
  float* bufT[2] = {fb + 2 * N_NODES * HD, fb + 3 * N_NODES * HD};
  float* aggBase = fb + (size_t)4 * N_NODES * HD;        // 4 * N*64
  unsigned* y4 = (unsigned*)(fb + (size_t)8 * N_NODES * HD);  // 4 * Y2ROW uints
  short* whh16 = (short*)(y4 + 4 * Y2ROW);               // 12 * 32768
  short* wih16 = whh16 + 12 * 32768;                     // 12 * 32768
  short* cw16 = wih16 + 12 * 32768;                      // 6 * 24576
  short* ehw16 = cw16 + 6 * 24576;                       // 32 * 2 * 512

  prep_all_kernel<<<(60928 + 4 * N_NODES + 255) / 256, 256, 0, stream>>>(
      Whh, Wih, Wl, Wr, Wg1, Wm1, Wm2, whh16, wih16, cw16, ehw16, y4, cnt);
  scatter_kernel<<<(4 * N_EDGES + 255) / 256, 256, 0, stream>>>(edges, cnt, pool);
  sortrows_kernel<<<(4 * N_NODES + 63) / 64, 64, 0, stream>>>(cnt, pool, nbr);
  encode_both_kernel<<<dim3(N_NODES / 4, 2), 256, 0, stream>>>(x_source, x_target,
      We_s1, be_s1, We_s2, be_s2, We_t1, be_t1, We_t2, be_t2, bufS[0], bufT[0]);

  int cur = 0;
  for (int L = 0; L < 3; ++L) {
    ygemm_mfma_kernel<<<dim3(N_NODES / 16, 4), 256, 0, stream>>>(bufS[cur], bufT[cur],
        wih16 + (size_t)L * 4 * 32768, y4);
    lstm_mfma_kernel<<<dim3(N_NODES / 16, 4), 256, 0, stream>>>(nbr, y4,
        whh16 + (size_t)L * 4 * 32768, bih + L * 1024, bhh + L * 1024, aggBase);
    combine_mfma_kernel<<<dim3(N_NODES / 16, 2), 256, 0, stream>>>(aggBase,
        cw16 + (size_t)L * 2 * 24576, bl + L * 256,
        bufS[cur], bufT[cur], L > 0 ? 1 : 0, bufS[1 - cur], bufT[1 - cur]);
    cur = 1 - cur;
  }

  edge_head_mfma_kernel<<<N_EDGES / 64, 256, 0, stream>>>(edges + 4 * N_EDGES,
      edges + 5 * N_EDGES, edge_attr, bufS[cur], bufT[cur], ehw16,
      bg1, Wg2, bg2, bm1, bm2, Wm3, bm3, out);
}

// Round 11
// 442.474 us; speedup vs baseline: 1.0611x; 1.0611x over previous
//
#include <hip/hip_runtime.h>

#define N_NODES 10000
#define N_EDGES 40000
#define HD 64
#define MAXD 12
#define CAP 32
#define Y2ROW ((size_t)(N_NODES + 1) * 128)  // per-edge-type y stride in uints (bf16-packed)
#define LOG2E 1.44269504f
#define XST 148  // edge-head LDS row stride (floats)

typedef __attribute__((ext_vector_type(8))) short short8;
typedef __attribute__((ext_vector_type(4))) float floatx4;

#define MFMA16(A, B, C) __builtin_amdgcn_mfma_f32_16x16x32_bf16(A, B, C, 0, 0, 0)

#if __has_builtin(__builtin_amdgcn_exp2f)
#define EXP2(x) __builtin_amdgcn_exp2f(x)
#else
#define EXP2(x) __expf((x) * 0.6931471806f)
#endif

__device__ __forceinline__ float sigmoidf_(float x) {
  return 1.0f / (1.0f + __expf(-x));
}
__device__ __forceinline__ float fma4(float4 w, float4 x, float a) {
  a = fmaf(w.x, x.x, a);
  a = fmaf(w.y, x.y, a);
  a = fmaf(w.z, x.z, a);
  return fmaf(w.w, x.w, a);
}

// split 8 consecutive fp32 into bf16 hi/lo fragments
__device__ __forceinline__ void split_frag(float4 a, float4 b, short8& hi, short8& lo) {
  float f[8] = {a.x, a.y, a.z, a.w, b.x, b.y, b.z, b.w};
  union { short8 v; unsigned d[4]; } H, L;
#pragma unroll
  for (int p = 0; p < 4; ++p) {
    unsigned u0 = __float_as_uint(f[2 * p]);
    unsigned u1 = __float_as_uint(f[2 * p + 1]);
    H.d[p] = (u0 >> 16) | (u1 & 0xFFFF0000u);
    float l0 = f[2 * p] - __uint_as_float(u0 & 0xFFFF0000u);
    float l1 = f[2 * p + 1] - __uint_as_float(u1 & 0xFFFF0000u);
    L.d[p] = (__float_as_uint(l0) >> 16) | (__float_as_uint(l1) & 0xFFFF0000u);
  }
  hi = H.v;
  lo = L.v;
}

// ---------------- adjacency build ----------------

__global__ void scatter_kernel(const int* __restrict__ edges, int* __restrict__ cnt,
                               int* __restrict__ pool) {
  int idx = blockIdx.x * 256 + threadIdx.x;
  if (idx >= 4 * N_EDGES) return;
  int et = idx / N_EDGES, e = idx - et * N_EDGES;
  int src = edges[(et * 2) * N_EDGES + e];
  int dst = edges[(et * 2 + 1) * N_EDGES + e];
  int slot = atomicAdd(&cnt[et * N_NODES + dst], 1);
  if (slot < CAP) pool[(et * N_NODES + dst) * CAP + slot] = src;
}

__global__ void sortrows_kernel(const int* __restrict__ cnt, const int* __restrict__ pool,
                                int* __restrict__ nbr) {
  __shared__ int buf[64][CAP + 1];
  int idx = blockIdx.x * 64 + threadIdx.x;
  if (idx >= 4 * N_NODES) return;
  int n = idx % N_NODES;
  int c = cnt[idx];
  if (c > CAP) c = CAP;
  int* a = buf[threadIdx.x];
  const int* row = pool + idx * CAP;
  for (int j = 0; j < c; ++j) a[j] = row[j] * 2;
  a[c] = n * 2 + 1;  // self loop sorts after equal-src originals (stable argsort semantics)
  ++c;
  for (int i2 = 1; i2 < c; ++i2) {
    int key = a[i2];
    int b = i2 - 1;
    while (b >= 0 && a[b] > key) { a[b + 1] = a[b]; --b; }
    a[b + 1] = key;
  }
  int* onbr = nbr + idx * MAXD;
  for (int t = 0; t < MAXD; ++t) onbr[t] = (t < c) ? (a[t] >> 1) : N_NODES;
}

// ---------------- fused weight prep ----------------

__device__ __forceinline__ void wfrag_body(const float* __restrict__ W,
                                           short* __restrict__ w16, int gid) {
  int lane = gid & 63;
  int combo = gid >> 6;
  int kc = combo & 1;
  int g = (combo >> 1) & 3;
  int w = (combo >> 3) & 3;
  int i = combo >> 5;
  float sc = (g == 2) ? (2.0f * LOG2E) : LOG2E;
  int gate = g * 64 + w * 16 + (lane & 15);
  int k0 = kc * 32 + (lane >> 4) * 8;
  const float* src = W + ((size_t)i * 256 + gate) * 64 + k0;
  float4 a = ((const float4*)src)[0];
  float4 b = ((const float4*)src)[1];
  a.x *= sc; a.y *= sc; a.z *= sc; a.w *= sc;
  b.x *= sc; b.y *= sc; b.z *= sc; b.w *= sc;
  short8 hi, lo;
  split_frag(a, b, hi, lo);
  short8* dst = (short8*)w16;
  dst[(combo * 2 + 0) * 64 + lane] = hi;
  dst[(combo * 2 + 1) * 64 + lane] = lo;
}

__device__ __forceinline__ void wfrag_body_noscale(const float* __restrict__ W,
                                                   short* __restrict__ w16, int gid) {
  int lane = gid & 63;
  int combo = gid >> 6;
  int kc = combo & 1;
  int g = (combo >> 1) & 3;
  int w = (combo >> 3) & 3;
  int i = combo >> 5;
  int gate = g * 64 + w * 16 + (lane & 15);
  int k0 = kc * 32 + (lane >> 4) * 8;
  const float* src = W + ((size_t)i * 256 + gate) * 64 + k0;
  float4 a = ((const float4*)src)[0];
  float4 b = ((const float4*)src)[1];
  short8 hi, lo;
  split_frag(a, b, hi, lo);
  short8* dst = (short8*)w16;
  dst[(combo * 2 + 0) * 64 + lane] = hi;
  dst[(combo * 2 + 1) * 64 + lane] = lo;
}

__device__ __forceinline__ void cw_body(const float* __restrict__ Wl,
    const float* __restrict__ Wr, short* __restrict__ cw, int gid) {
  int lane = gid & 63;
  int rest = gid >> 6;
  int combo = rest & 7;
  int mat = (rest >> 3) % 3;
  int pair = rest / 24;
  int L = pair >> 1, side = pair & 1;
  int iA = L * 4 + (side ? 1 : 0);
  int iB = L * 4 + (side ? 2 : 3);
  int wp = combo >> 1, kc = combo & 1;
  int row = wp * 16 + (lane & 15);
  int k0 = kc * 32 + (lane >> 4) * 8;
  float4 a, b;
  if (mat == 0) {
    const float* s = Wl + ((size_t)iA * 64 + row) * 64 + k0;
    a = ((const float4*)s)[0]; b = ((const float4*)s)[1];
  } else if (mat == 1) {
    const float* s = Wl + ((size_t)iB * 64 + row) * 64 + k0;
    a = ((const float4*)s)[0]; b = ((const float4*)s)[1];
  } else {
    const float* sA = Wr + ((size_t)iA * 64 + row) * 64 + k0;
    const float* sB = Wr + ((size_t)iB * 64 + row) * 64 + k0;
    float4 a1 = ((const float4*)sA)[0], b1 = ((const float4*)sA)[1];
    float4 a2 = ((const float4*)sB)[0], b2 = ((const float4*)sB)[1];
    a.x = a1.x + a2.x; a.y = a1.y + a2.y; a.z = a1.z + a2.z; a.w = a1.w + a2.w;
    b.x = b1.x + b2.x; b.y = b1.y + b2.y; b.z = b1.z + b2.z; b.w = b1.w + b2.w;
  }
  short8 hi, lo;
  split_frag(a, b, hi, lo);
  short8* dst = (short8*)cw;
  int base = ((pair * 3 + mat) * 8 + combo) * 2;
  dst[(base + 0) * 64 + lane] = hi;
  dst[(base + 1) * 64 + lane] = lo;
}

__device__ __forceinline__ void eh_body(const float* __restrict__ Wg1,
    const float* __restrict__ Wm1, const float* __restrict__ Wm2,
    short* __restrict__ ehw16, int gid) {
  int lane = gid & 63;
  int combo = gid >> 6;
  int n = lane & 15, quad = lane >> 4;
  int mat, wp, kc;
  if (combo < 16) { mat = 0; wp = combo >> 2; kc = combo & 3; }
  else if (combo < 28) { int c2 = combo - 16; mat = 1; wp = c2 / 3; kc = c2 % 3; }
  else { int c2 = combo - 28; mat = 2; wp = c2 >> 1; kc = c2 & 1; }
  int row = wp * 16 + n;
  int k0 = kc * 32 + quad * 8;
  float4 a = {0.f, 0.f, 0.f, 0.f}, b = {0.f, 0.f, 0.f, 0.f};
  if (mat == 0) {
    const float* s = Wg1 + (size_t)row * 128 + k0;
    a = ((const float4*)s)[0]; b = ((const float4*)s)[1];
  } else if (mat == 1) {
    if (k0 + 8 <= 80) {
      const float* s = Wm1 + (size_t)row * 80 + k0;
      a = ((const float4*)s)[0]; b = ((const float4*)s)[1];
    }
  } else {
    const float* s = Wm2 + (size_t)row * 64 + k0;
    a = ((const float4*)s)[0]; b = ((const float4*)s)[1];
  }
  short8 hi, lo;
  split_frag(a, b, hi, lo);
  short8* dst = (short8*)ehw16;
  dst[(combo * 2 + 0) * 64 + lane] = hi;
  dst[(combo * 2 + 1) * 64 + lane] = lo;
}

__global__ __launch_bounds__(256) void prep_all_kernel(
    const float* __restrict__ Whh, const float* __restrict__ Wih,
    const float* __restrict__ Wl, const float* __restrict__ Wr,
    const float* __restrict__ Wg1, const float* __restrict__ Wm1,
    const float* __restrict__ Wm2,
    short* __restrict__ whh16, short* __restrict__ wih16, short* __restrict__ cw16,
    short* __restrict__ ehw16, unsigned* __restrict__ ybase, int* __restrict__ cnt) {
  int gid = blockIdx.x * 256 + threadIdx.x;
  if (gid < 24576) {
    wfrag_body(Whh, whh16, gid);
  } else if (gid < 49152) {
    wfrag_body_noscale(Wih, wih16, gid - 24576);
  } else if (gid < 58368) {
    cw_body(Wl, Wr, cw16, gid - 49152);
  } else if (gid < 60416) {
    eh_body(Wg1, Wm1, Wm2, ehw16, gid - 58368);
  } else if (gid < 60928) {
    int t = gid - 60416;  // 4 ets x 128 uints: dummy zero row
    int et = t >> 7, col = t & 127;
    ybase[(size_t)et * Y2ROW + (size_t)N_NODES * 128 + col] = 0u;
  } else if (gid < 60928 + 4 * N_NODES) {
    cnt[gid - 60928] = 0;  // fused cnt memset
  }
}

// ---------------- node encoders ----------------

template <int IN>
__device__ __forceinline__ void encode_body(const float* __restrict__ x,
    const float* __restrict__ W1, const float* __restrict__ b1,
    const float* __restrict__ W2, const float* __restrict__ b2, float* __restrict__ out) {
  __shared__ float xs[4][IN];
  __shared__ float h1[4][HD];
  int w = threadIdx.x >> 6, l = threadIdx.x & 63;
  int n = blockIdx.x * 4 + w;
  if (l < IN) xs[w][l] = x[n * IN + l];
  __syncthreads();
  float acc = b1[l];
#pragma unroll
  for (int k = 0; k < IN; ++k) acc = fmaf(xs[w][k], W1[l * IN + k], acc);
  h1[w][l] = fmaxf(acc, 0.0f);
  __syncthreads();
  float acc2 = b2[l];
#pragma unroll
  for (int k = 0; k < HD; ++k) acc2 = fmaf(h1[w][k], W2[l * HD + k], acc2);
  out[n * HD + l] = acc2;
}

__global__ __launch_bounds__(256) void encode_both_kernel(
    const float* __restrict__ xs0, const float* __restrict__ xt0,
    const float* __restrict__ Ws1, const float* __restrict__ bs1,
    const float* __restrict__ Ws2, const float* __restrict__ bs2,
    const float* __restrict__ Wt1, const float* __restrict__ bt1,
    const float* __restrict__ Wt2, const float* __restrict__ bt2,
    float* __restrict__ outS, float* __restrict__ outT) {
  if (blockIdx.y == 0) encode_body<32>(xs0, Ws1, bs1, Ws2, bs2, outS);
  else encode_body<24>(xt0, Wt1, bt1, Wt2, bt2, outT);
}

// ---------------- y = x @ Wih.T via MFMA; packed bf16 out; XCD-et swizzle ----------------
// 1-D grid of 2504 blocks: et = (bid&7)>>1 so one edge type maps to 2 XCDs
// (blockIdx%8 ~ XCD heuristic) — producer leaves y resident in consumer's L2.

__global__ __launch_bounds__(256) void ygemm_mfma_kernel(const float* __restrict__ xs0,
    const float* __restrict__ xt0, const short* __restrict__ wih16L, unsigned* __restrict__ ybase) {
  __shared__ __align__(16) float xS[16][68];
  __shared__ __align__(16) float pS[16][260];
  int bid = blockIdx.x;
  int xg = bid & 7;
  int et = xg >> 1;
  int blk = (bid >> 3) * 2 + (xg & 1);
  if (blk >= 625) return;
  const float* x = (et == 0 || et == 2) ? xs0 : xt0;
  const short8* wf = (const short8*)(wih16L + (size_t)et * 32768);
  unsigned* y = ybase + (size_t)et * Y2ROW;
  int tid = threadIdx.x, w = tid >> 6, l = tid & 63;
  int quad = l >> 4, n = l & 15;
  int n0 = blk * 16;
  {
    int node = tid >> 4, f4 = tid & 15;
    float4 v = *(const float4*)(x + (size_t)(n0 + node) * 64 + f4 * 4);
    *(float4*)&xS[node][f4 * 4] = v;
  }
  short8 Bh[4][2], Bl[4][2];
#pragma unroll
  for (int wp = 0; wp < 4; ++wp)
#pragma unroll
    for (int kc = 0; kc < 2; ++kc) {
      int combo = (wp * 4 + w) * 2 + kc;
      Bh[wp][kc] = wf[(combo * 2 + 0) * 64 + l];
      Bl[wp][kc] = wf[(combo * 2 + 1) * 64 + l];
    }
  __syncthreads();
  short8 Ah[2], Al[2];
  {
    const float* hp = &xS[n][quad * 8];
    float4 q0 = *(const float4*)hp, q1 = *(const float4*)(hp + 4);
    float4 q2 = *(const float4*)(hp + 32), q3 = *(const float4*)(hp + 36);
    split_frag(q0, q1, Ah[0], Al[0]);
    split_frag(q2, q3, Ah[1], Al[1]);
  }
  floatx4 acc[4];
#pragma unroll
  for (int wp = 0; wp < 4; ++wp) {
    floatx4 a = {0.f, 0.f, 0.f, 0.f};
    a = MFMA16(Ah[0], Bh[wp][0], a);
    a = MFMA16(Ah[1], Bh[wp][1], a);
    a = MFMA16(Al[0], Bh[wp][0], a);
    a = MFMA16(Al[1], Bh[wp][1], a);
    a = MFMA16(Ah[0], Bl[wp][0], a);
    a = MFMA16(Ah[1], Bl[wp][1], a);
    acc[wp] = a;
  }
#pragma unroll
  for (int wp = 0; wp < 4; ++wp)
#pragma unroll
    for (int r = 0; r < 4; ++r)
      pS[quad * 4 + r][(wp * 16 + n) * 4 + w] = acc[wp][r];
  __syncthreads();
#pragma unroll
  for (int cc = 0; cc < 4; ++cc) {
    int g4 = cc * 256 + tid;
    int node = g4 >> 6, u = g4 & 63;
    const float* p = &pS[node][u * 4];
    unsigned r0 = __float_as_uint(p[0]) + 0x8000u;
    unsigned r1 = __float_as_uint(p[1]) + 0x8000u;
    unsigned r2 = __float_as_uint(p[2]) + 0x8000u;
    unsigned r3 = __float_as_uint(p[3]) + 0x8000u;
    uint2 v;
    v.x = __builtin_amdgcn_perm(r1, r0, 0x07060302u);
    v.y = __builtin_amdgcn_perm(r3, r2, 0x07060302u);
    ((uint2*)(y + (size_t)(n0 + node) * 128))[u] = v;
  }
}

// ---------------- SAGE-LSTM aggregation, MFMA split-bf16, XCD-et swizzle ----------------
// R9 body (best known). et = (bid&7)>>1: each XCD's L2 holds ~one et's 5.1 MB y.

__global__ __launch_bounds__(256) void lstm_mfma_kernel(const int* __restrict__ nbrAll,
    const unsigned* __restrict__ ybase, const short* __restrict__ whh16L,
    const float* __restrict__ bihL, const float* __restrict__ bhhL, float* __restrict__ aggBase) {
  __shared__ __align__(16) unsigned pkS[2][16 * 68];
  __shared__ int nbS[16][MAXD];
  int bid = blockIdx.x;
  int xg = bid & 7;
  int et = xg >> 1;
  int blk = (bid >> 3) * 2 + (xg & 1);
  if (blk >= 625) return;
  const int* nbr = nbrAll + (size_t)et * N_NODES * MAXD;
  const uint2* y2 = (const uint2*)(ybase + (size_t)et * Y2ROW);
  const short* whh16 = whh16L + (size_t)et * 32768;
  const float* bih = bihL + et * 256;
  const float* bhh = bhhL + et * 256;
  float* agg = aggBase + (size_t)et * N_NODES * HD;
  int tid = threadIdx.x, w = tid >> 6, l = tid & 63;
  int quad = l >> 4, n = l & 15, u = w * 16 + n;
  int n0 = blk * 16;
  if (tid < 16 * MAXD) ((int*)nbS)[tid] = nbr[n0 * MAXD + tid];
  short8 Bh[4][2], Bl[4][2];
  {
    const short8* wf = (const short8*)whh16;
#pragma unroll
    for (int g = 0; g < 4; ++g)
#pragma unroll
      for (int kc = 0; kc < 2; ++kc) {
        int combo = (w * 4 + g) * 2 + kc;
        Bh[g][kc] = wf[(combo * 2 + 0) * 64 + l];
        Bl[g][kc] = wf[(combo * 2 + 1) * 64 + l];
      }
  }
  float bs[4];
#pragma unroll
  for (int g = 0; g < 4; ++g)
    bs[g] = (bih[g * 64 + u] + bhh[g * 64 + u]) * ((g == 2) ? (2.0f * LOG2E) : LOG2E);
  float c[4] = {0.f, 0.f, 0.f, 0.f}, h[4];
  short8 Ah[2], Al[2];
#pragma unroll
  for (int kc = 0; kc < 2; ++kc) { Ah[kc] = (short8)0; Al[kc] = (short8)0; }
  __syncthreads();
  uint2 Y[4];
#pragma unroll
  for (int r = 0; r < 4; ++r) Y[r] = y2[(size_t)nbS[quad * 4 + r][0] * 64 + u];
  for (int t = 0; t < MAXD; ++t) {
    float yg[4][4];
#pragma unroll
    for (int r = 0; r < 4; ++r) {
      yg[0][r] = __uint_as_float(Y[r].x << 16);
      yg[1][r] = __uint_as_float(Y[r].x & 0xFFFF0000u);
      yg[2][r] = __uint_as_float(Y[r].y << 16);
      yg[3][r] = __uint_as_float(Y[r].y & 0xFFFF0000u);
    }
    floatx4 acc[4];
#pragma unroll
    for (int g = 0; g < 4; ++g) {
      floatx4 a = {yg[g][0], yg[g][1], yg[g][2], yg[g][3]};
      a = MFMA16(Ah[0], Bh[g][0], a);
      a = MFMA16(Ah[1], Bh[g][1], a);
      a = MFMA16(Al[0], Bh[g][0], a);
      a = MFMA16(Al[1], Bh[g][1], a);
      a = MFMA16(Ah[0], Bl[g][0], a);
      a = MFMA16(Ah[1], Bl[g][1], a);
      acc[g] = a;
    }
    if (t + 1 < MAXD) {
#pragma unroll
      for (int r = 0; r < 4; ++r) Y[r] = y2[(size_t)nbS[quad * 4 + r][t + 1] * 64 + u];
    }
    int buf = (t + 1) & 1;
#pragma unroll
    for (int r = 0; r < 4; ++r) {
      float gi = acc[0][r] + bs[0];
      float gf = acc[1][r] + bs[1];
      float gg = acc[2][r] + bs[2];
      float go = acc[3][r] + bs[3];
      float a_ = EXP2(-gi);
      float b_ = EXP2(fminf(-gg, 60.f));
      float f_ = EXP2(-gf);
      float o_ = EXP2(-go);
      float p1 = 1.f + a_, p2 = 1.f + b_, p3 = 1.f + f_;
      float d1 = p1 * p2;
      float num = fmaf(c[r], d1, (1.f - b_) * p3);
      c[r] = num * __builtin_amdgcn_rcpf(p3 * d1);
      float e_ = EXP2(c[r] * (-2.0f * LOG2E));
      h[r] = (1.f - e_) * __builtin_amdgcn_rcpf((1.f + e_) * (1.f + o_));
      unsigned ub = __float_as_uint(h[r]);
      float lo = h[r] - __uint_as_float(ub & 0xFFFF0000u);
      pkS[buf][(quad * 4 + r) * 68 + u] =
          __builtin_amdgcn_perm(ub, __float_as_uint(lo), 0x07060302u);
    }
    __syncthreads();
    if (t + 1 < MAXD) {
#pragma unroll
      for (int kc = 0; kc < 2; ++kc) {
        const unsigned* pb = &pkS[buf][n * 68 + kc * 32 + quad * 8];
        uint4 qa = *(const uint4*)pb;
        uint4 qb = *(const uint4*)(pb + 4);
        union { short8 s; unsigned d[4]; } H, L;
        H.d[0] = __builtin_amdgcn_perm(qa.y, qa.x, 0x07060302u);
        H.d[1] = __builtin_amdgcn_perm(qa.w, qa.z, 0x07060302u);
        H.d[2] = __builtin_amdgcn_perm(qb.y, qb.x, 0x07060302u);
        H.d[3] = __builtin_amdgcn_perm(qb.w, qb.z, 0x07060302u);
        L.d[0] = __builtin_amdgcn_perm(qa.y, qa.x, 0x05040100u);
        L.d[1] = __builtin_amdgcn_perm(qa.w, qa.z, 0x05040100u);
        L.d[2] = __builtin_amdgcn_perm(qb.y, qb.x, 0x05040100u);
        L.d[3] = __builtin_amdgcn_perm(qb.w, qb.z, 0x05040100u);
        Ah[kc] = H.s;
        Al[kc] = L.s;
      }
    }
  }
#pragma unroll
  for (int r = 0; r < 4; ++r)
    agg[(size_t)(n0 + quad * 4 + r) * HD + u] = h[r];
}

// ---------------- combine via MFMA ----------------

__global__ __launch_bounds__(256) void combine_mfma_kernel(const float* __restrict__ aggBase,
    const short* __restrict__ cwL, const float* __restrict__ blL,
    const float* __restrict__ xS0, const float* __restrict__ xT0, int has_res,
    float* __restrict__ outS, float* __restrict__ outT) {
  __shared__ __align__(16) float tS[3][16][68];
  int side = blockIdx.y;
  int etA = side ? 1 : 0, etB = side ? 2 : 3;
  const float* srcs[3];
  srcs[0] = aggBase + (size_t)etA * N_NODES * HD;
  srcs[1] = aggBase + (size_t)etB * N_NODES * HD;
  srcs[2] = side ? xT0 : xS0;
  float* out = side ? outT : outS;
  const short8* wf = (const short8*)cwL + (size_t)side * 3072;
  const float* blA = blL + etA * 64;
  const float* blB = blL + etB * 64;
  int tid = threadIdx.x, w = tid >> 6, l = tid & 63;
  int quad = l >> 4, n = l & 15;
  int n0 = blockIdx.x * 16;
  {
    int node = tid >> 4, f4 = tid & 15;
#pragma unroll
    for (int m = 0; m < 3; ++m) {
      float4 v = *(const float4*)(srcs[m] + (size_t)(n0 + node) * 64 + f4 * 4);
      *(float4*)&tS[m][node][f4 * 4] = v;
    }
  }
  short8 Bh[3][2], Bl[3][2];
#pragma unroll
  for (int m = 0; m < 3; ++m)
#pragma unroll
    for (int kc = 0; kc < 2; ++kc) {
      int base = (m * 8 + w * 2 + kc) * 2;
      Bh[m][kc] = wf[(base + 0) * 64 + l];
      Bl[m][kc] = wf[(base + 1) * 64 + l];
    }
  float bsum = blA[w * 16 + n] + blB[w * 16 + n];
  __syncthreads();
  floatx4 a = {0.f, 0.f, 0.f, 0.f};
#pragma unroll
  for (int m = 0; m < 3; ++m) {
    short8 Ah[2], Al[2];
    const float* hp = &tS[m][n][quad * 8];
    float4 q0 = *(const float4*)hp, q1 = *(const float4*)(hp + 4);
    float4 q2 = *(const float4*)(hp + 32), q3 = *(const float4*)(hp + 36);
    split_frag(q0, q1, Ah[0], Al[0]);
    split_frag(q2, q3, Ah[1], Al[1]);
    a = MFMA16(Ah[0], Bh[m][0], a);
    a = MFMA16(Ah[1], Bh[m][1], a);
    a = MFMA16(Al[0], Bh[m][0], a);
    a = MFMA16(Al[1], Bh[m][1], a);
    a = MFMA16(Ah[0], Bl[m][0], a);
    a = MFMA16(Ah[1], Bl[m][1], a);
  }
#pragma unroll
  for (int r = 0; r < 4; ++r) {
    int node = quad * 4 + r;
    float v = 0.5f * (a[r] + bsum);
    if (has_res) v += tS[2][node][w * 16 + n];
    out[(size_t)(n0 + node) * 64 + w * 16 + n] = fmaxf(v, 0.f);
  }
}

// ---------------- edge head via MFMA ----------------

__global__ __launch_bounds__(256) void edge_head_mfma_kernel(
    const int* __restrict__ esrc, const int* __restrict__ edst, const float* __restrict__ ea,
    const float* __restrict__ s3, const float* __restrict__ t3,
    const short* __restrict__ ehw16,
    const float* __restrict__ bg1, const float* __restrict__ Wg2,
    const float* __restrict__ bg2, const float* __restrict__ bm1,
    const float* __restrict__ bm2, const float* __restrict__ Wm3,
    const float* __restrict__ bm3, float* __restrict__ out) {
  __shared__ __align__(16) float xS[64][XST];
  __shared__ float gP[4][64];
  int tid = threadIdx.x, w = tid >> 6, l = tid & 63;
  int quad = l >> 4, n = l & 15;
  int e0 = blockIdx.x * 64;
  const short8* wf = (const short8*)ehw16;
  for (int idx = tid; idx < 2048; idx += 256) {
    int e = idx >> 5, kk = idx & 31;
    float4 v;
    if (kk < 16) v = ((const float4*)(s3 + (size_t)esrc[e0 + e] * 64))[kk];
    else         v = ((const float4*)(t3 + (size_t)edst[e0 + e] * 64))[kk - 16];
    *(float4*)&xS[e][kk * 4] = v;
  }
  {
    int e = tid >> 2, kk = tid & 3;
    *(float4*)&xS[e][128 + kk * 4] = ((const float4*)(ea + (size_t)(e0 + e) * 16))[kk];
  }
  __syncthreads();
  {
    short8 Bh[4], Bl[4];
#pragma unroll
    for (int kc = 0; kc < 4; ++kc) {
      int cb = w * 4 + kc;
      Bh[kc] = wf[(cb * 2 + 0) * 64 + l];
      Bl[kc] = wf[(cb * 2 + 1) * 64 + l];
    }
    float bg = bg1[w * 16 + n];
    float wg2l = Wg2[w * 16 + n];
    float red[4][4];
#pragma unroll
    for (int mt = 0; mt < 4; ++mt) {
      floatx4 a = {bg, bg, bg, bg};
#pragma unroll
      for (int kc = 0; kc < 4; ++kc) {
        const float* hp = &xS[mt * 16 + n][kc * 32 + quad * 8];
        float4 q0 = *(const float4*)hp, q1 = *(const float4*)(hp + 4);
        short8 Ah, Al;
        split_frag(q0, q1, Ah, Al);
        a = MFMA16(Ah, Bh[kc], a);
        a = MFMA16(Al, Bh[kc], a);
        a = MFMA16(Ah, Bl[kc], a);
      }
#pragma unroll
      for (int r = 0; r < 4; ++r) red[mt][r] = fmaxf(a[r], 0.f) * wg2l;
    }
#pragma unroll
    for (int mt = 0; mt < 4; ++mt)
#pragma unroll
      for (int r = 0; r < 4; ++r) {
#pragma unroll
        for (int off = 1; off < 16; off <<= 1)
          red[mt][r] += __shfl_xor(red[mt][r], off);
      }
#pragma unroll
    for (int mt = 0; mt < 4; ++mt)
#pragma unroll
      for (int r = 0; r < 4; ++r)
        if (n == mt * 4 + r) gP[w][mt * 16 + quad * 4 + r] = red[mt][r];
  }
  __syncthreads();
  float gv[4];
  {
    float b2 = bg2[0];
#pragma unroll
    for (int mt = 0; mt < 4; ++mt) {
      int e = mt * 16 + n;
      float p = gP[0][e] + gP[1][e] + gP[2][e] + gP[3][e] + b2;
      gv[mt] = sigmoidf_(p);
    }
  }
  floatx4 acc2[4];
  {
    short8 Bh[3], Bl[3];
#pragma unroll
    for (int kc = 0; kc < 3; ++kc) {
      int cb = 16 + w * 3 + kc;
      Bh[kc] = wf[(cb * 2 + 0) * 64 + l];
      Bl[kc] = wf[(cb * 2 + 1) * 64 + l];
    }
    float bm = bm1[w * 16 + n];
#pragma unroll
    for (int mt = 0; mt < 4; ++mt) {
      int e = mt * 16 + n;
      float g = gv[mt];
      floatx4 a = {bm, bm, bm, bm};
#pragma unroll
      for (int kc = 0; kc < 2; ++kc) {
        const float* sp = &xS[e][kc * 32 + quad * 8];
        float4 s0 = *(const float4*)sp, s1 = *(const float4*)(sp + 4);
        float4 t0 = *(const float4*)(sp + 64), t1 = *(const float4*)(sp + 68);
        float4 e0v, e1v;
        e0v.x = fmaf(g, s0.x - t0.x, t0.x); e0v.y = fmaf(g, s0.y - t0.y, t0.y);
        e0v.z = fmaf(g, s0.z - t0.z, t0.z); e0v.w = fmaf(g, s0.w - t0.w, t0.w);
        e1v.x = fmaf(g, s1.x - t1.x, t1.x); e1v.y = fmaf(g, s1.y - t1.y, t1.y);
        e1v.z = fmaf(g, s1.z - t1.z, t1.z); e1v.w = fmaf(g, s1.w - t1.w, t1.w);
        short8 Ah, Al;
        split_frag(e0v, e1v, Ah, Al);
        a = MFMA16(Ah, Bh[kc], a);
        a = MFMA16(Al, Bh[kc], a);
        a = MFMA16(Ah, Bl[kc], a);
      }
      {
        float4 z0 = {0.f, 0.f, 0.f, 0.f}, z1 = {0.f, 0.f, 0.f, 0.f};
        if (quad < 2) {
          const float* ap = &xS[e][128 + quad * 8];
          z0 = *(const float4*)ap;
          z1 = *(const float4*)(ap + 4);
        }
        short8 Ah, Al;
        split_frag(z0, z1, Ah, Al);
        a = MFMA16(Ah, Bh[2], a);
        a = MFMA16(Al, Bh[2], a);
        a = MFMA16(Ah, Bl[2], a);
      }
      acc2[mt] = a;
    }
  }
  __syncthreads();
#pragma unroll
  for (int mt = 0; mt < 4; ++mt)
#pragma unroll
    for (int r = 0; r < 4; ++r)
      xS[mt * 16 + quad * 4 + r][w * 16 + n] = fmaxf(acc2[mt][r], 0.f);
  __syncthreads();
  {
    int s = w & 1, mtb = (w >> 1) * 2;
    short8 Bh[2], Bl[2];
#pragma unroll
    for (int kc = 0; kc < 2; ++kc) {
      int cb = 28 + s * 2 + kc;
      Bh[kc] = wf[(cb * 2 + 0) * 64 + l];
      Bl[kc] = wf[(cb * 2 + 1) * 64 + l];
    }
    float bm = bm2[s * 16 + n];
#pragma unroll
    for (int mi = 0; mi < 2; ++mi) {
      int mt = mtb + mi;
      int e = mt * 16 + n;
      floatx4 a = {bm, bm, bm, bm};
#pragma unroll
      for (int kc = 0; kc < 2; ++kc) {
        const float* sp = &xS[e][kc * 32 + quad * 8];
        float4 q0 = *(const float4*)sp, q1 = *(const float4*)(sp + 4);
        short8 Ah, Al;
        split_frag(q0, q1, Ah, Al);
        a = MFMA16(Ah, Bh[kc], a);
        a = MFMA16(Al, Bh[kc], a);
        a = MFMA16(Ah, Bl[kc], a);
      }
#pragma unroll
      for (int r = 0; r < 4; ++r)
        xS[mt * 16 + quad * 4 + r][64 + s * 16 + n] = fmaxf(a[r], 0.f);
    }
  }
  __syncthreads();
  if (tid < 128) {
    int e = tid >> 1, j = tid & 1;
    const float4* hp = (const float4*)&xS[e][64];
    const float4* w3 = (const float4*)(Wm3 + j * 32);
    float a = bm3[j];
#pragma unroll
    for (int kk = 0; kk < 8; ++kk) a = fma4(w3[kk], hp[kk], a);
    out[(e0 + e) * 2 + j] = a;
  }
}

// ---------------- host orchestration ----------------

extern "C" void kernel_launch(void* const* d_in, const int* in_sizes, int n_in, void* d_out,
                              int out_size, void* d_ws, size_t ws_size, hipStream_t stream) {
  const float* x_source = (const float*)d_in[0];
  const float* x_target = (const float*)d_in[1];
  const int* edges = (const int*)d_in[2];
  const float* edge_attr = (const float*)d_in[3];
  const float* We_s1 = (const float*)d_in[4];
  const float* be_s1 = (const float*)d_in[5];
  const float* We_s2 = (const float*)d_in[6];
  const float* be_s2 = (const float*)d_in[7];
  const float* We_t1 = (const float*)d_in[8];
  const float* be_t1 = (const float*)d_in[9];
  const float* We_t2 = (const float*)d_in[10];
  const float* be_t2 = (const float*)d_in[11];
  const float* Wih = (const float*)d_in[12];
  const float* Whh = (const float*)d_in[13];
  const float* bih = (const float*)d_in[14];
  const float* bhh = (const float*)d_in[15];
  const float* Wl = (const float*)d_in[16];
  const float* bl = (const float*)d_in[17];
  const float* Wr = (const float*)d_in[18];
  const float* Wg1 = (const float*)d_in[19];
  const float* bg1 = (const float*)d_in[20];
  const float* Wg2 = (const float*)d_in[21];
  const float* bg2 = (const float*)d_in[22];
  const float* Wm1 = (const float*)d_in[23];
  const float* bm1 = (const float*)d_in[24];
  const float* Wm2 = (const float*)d_in[25];
  const float* bm2 = (const float*)d_in[26];
  const float* Wm3 = (const float*)d_in[27];
  const float* bm3 = (const float*)d_in[28];
  float* out = (float*)d_out;

  int* nbr = (int*)d_ws;                       // 4*N*12
  int* cnt = nbr + 4 * N_NODES * MAXD;         // 4*N
  int* pool = cnt + 4 * N_NODES;               // 4*N*CAP
  float* fb = (float*)(pool + 4 * N_NODES * CAP);
  float* bufS[2] = {fb, fb + N_NODES * HD};
  float* bufT[2] = {fb + 2 * N_NODES * HD, fb + 3 * N_NODES * HD};
  float* aggBase = fb + (size_t)4 * N_NODES * HD;        // 4 * N*64
  unsigned* y4 = (unsigned*)(fb + (size_t)8 * N_NODES * HD);  // 4 * Y2ROW uints
  short* whh16 = (short*)(y4 + 4 * Y2ROW);               // 12 * 32768
  short* wih16 = whh16 + 12 * 32768;                     // 12 * 32768
  short* cw16 = wih16 + 12 * 32768;                      // 6 * 24576
  short* ehw16 = cw16 + 6 * 24576;                       // 32 * 2 * 512

  prep_all_kernel<<<(60928 + 4 * N_NODES + 255) / 256, 256, 0, stream>>>(
      Whh, Wih, Wl, Wr, Wg1, Wm1, Wm2, whh16, wih16, cw16, ehw16, y4, cnt);
  scatter_kernel<<<(4 * N_EDGES + 255) / 256, 256, 0, stream>>>(edges, cnt, pool);
  sortrows_kernel<<<(4 * N_NODES + 63) / 64, 64, 0, stream>>>(cnt, pool, nbr);
  encode_both_kernel<<<dim3(N_NODES / 4, 2), 256, 0, stream>>>(x_source, x_target,
      We_s1, be_s1, We_s2, be_s2, We_t1, be_t1, We_t2, be_t2, bufS[0], bufT[0]);

  int cur = 0;
  for (int L = 0; L < 3; ++L) {
    ygemm_mfma_kernel<<<2504, 256, 0, stream>>>(bufS[cur], bufT[cur],
        wih16 + (size_t)L * 4 * 32768, y4);
    lstm_mfma_kernel<<<2504, 256, 0, stream>>>(nbr, y4,
        whh16 + (size_t)L * 4 * 32768, bih + L * 1024, bhh + L * 1024, aggBase);
    combine_mfma_kernel<<<dim3(N_NODES / 16, 2), 256, 0, stream>>>(aggBase,
        cw16 + (size_t)L * 2 * 24576, bl + L * 256,
        bufS[cur], bufT[cur], L > 0 ? 1 : 0, bufS[1 - cur], bufT[1 - cur]);
    cur = 1 - cur;
  }

  edge_head_mfma_kernel<<<N_EDGES / 64, 256, 0, stream>>>(edges + 4 * N_EDGES,
      edges + 5 * N_EDGES, edge_attr, bufS[cur], bufT[cur], ehw16,
      bg1, Wg2, bg2, bm1, bm2, Wm3, bm3, out);
}